// Round 10
// baseline (347.731 us; speedup 1.0000x reference)
//
#include <hip/hip_runtime.h>

#define F_ 8
#define C_ 128
#define H_ 96
#define W_ 96
#define P_ (H_*W_)   // 9216
#define I_ 64
#define T_ 17
#define KK_ (F_*T_)  // 136

// compile-time tap offsets (full unroll -> immediates) — used by k_scores / k_yr
__device__ constexpr int DY[T_] = {-1,-1,-1, 0,0,0, 1,1,1, -3,-3,-3, 0,0, 3,3,3};
__device__ constexpr int DX[T_] = {-1, 0, 1,-1,0,1,-1,0,1, -3, 0, 3,-3,3,-3,0,3};

// dy-grouped tap order for k_y (consecutive taps share cache lines; CK = original k)
__constant__ int CDY[T_] = {-3,-3,-3, -1,-1,-1,  0, 0,0,0, 0,  1,1,1,  3, 3, 3};
__constant__ int CDX[T_] = {-3, 0, 3, -1, 0, 1, -3,-1,0,1, 3, -1,0,1, -3, 0, 3};
__constant__ int CK [T_] = { 9,10,11,  0, 1, 2, 12, 3,4,5,13,  6,7,8, 14,15,16};

typedef unsigned short u16;
typedef u16 u16x8 __attribute__((ext_vector_type(8)));

__device__ __forceinline__ float b2f(u16 u) { return __uint_as_float(((unsigned)u) << 16); }
__device__ __forceinline__ u16 f2b(float f) {
    unsigned u = __float_as_uint(f);
    u += 0x7fff + ((u >> 16) & 1);   // RNE
    return (u16)(u >> 16);
}

// vt[c] = sum_i wt[i]*rtw[i,c]; u[c] = sum_i wp[i]*rpw[i,c]; ct[0]=wt.rtb; ct[1]=wp.rpb
__global__ __launch_bounds__(128) void k_prep(const float* __restrict__ rtw,
                                              const float* __restrict__ rpw,
                                              const float* __restrict__ rtb,
                                              const float* __restrict__ rpb,
                                              const float* __restrict__ cp,
                                              float* __restrict__ vt,
                                              float* __restrict__ u,
                                              float* __restrict__ ct) {
    int c = threadIdx.x;  // 128
    float a = 0.f, b2 = 0.f;
    for (int i = 0; i < I_; ++i) {
        a  += cp[i]      * rtw[i*C_ + c];
        b2 += cp[I_ + i] * rpw[i*C_ + c];
    }
    vt[c] = a; u[c] = b2;
    if (c == 0) { float s = 0.f; for (int i = 0; i < I_; ++i) s += cp[i]      * rtb[i]; ct[0] = s; }
    if (c == 1) { float s = 0.f; for (int i = 0; i < I_; ++i) s += cp[I_ + i] * rpb[i]; ct[1] = s; }
}

// 6 weight transposes: 0-3: [I,C]->[C][I] (g,th,ph,rg); 4-5: [C,I]->[I][C] (W,rW)
__global__ __launch_bounds__(256) void k_tr(const float* __restrict__ g_w,
                                            const float* __restrict__ th_w,
                                            const float* __restrict__ ph_w,
                                            const float* __restrict__ rg_w,
                                            const float* __restrict__ W_w,
                                            const float* __restrict__ rW_w,
                                            float* __restrict__ gT,
                                            float* __restrict__ thT,
                                            float* __restrict__ phT,
                                            float* __restrict__ rgT,
                                            float* __restrict__ WT,
                                            float* __restrict__ rWT) {
    int which = blockIdx.y;
    int idx = blockIdx.x * 256 + threadIdx.x;
    const float* src; float* dst; int Cc;
    if      (which == 0) { src = g_w;  dst = gT;  Cc = C_; }
    else if (which == 1) { src = th_w; dst = thT; Cc = C_; }
    else if (which == 2) { src = ph_w; dst = phT; Cc = C_; }
    else if (which == 3) { src = rg_w; dst = rgT; Cc = C_; }
    else if (which == 4) { src = W_w;  dst = WT;  Cc = I_; }
    else                 { src = rW_w; dst = rWT; Cc = I_; }
    int R = (C_*I_) / Cc;
    int r = idx / Cc, c2 = idx % Cc;
    dst[c2 * R + r] = src[idx];
}

// three convs on x -> bf16 [f][i][p]; 4px/thread via float4, 32 i per thread
// Folds Bf (fp32) into proj==2,y==1
__global__ __launch_bounds__(256) void k_conv3(const float* __restrict__ x,
                                               const float* __restrict__ w0,
                                               const float* __restrict__ w1,
                                               const float* __restrict__ w2,
                                               const float* __restrict__ b0,
                                               const float* __restrict__ b1,
                                               const float* __restrict__ b2,
                                               const float* __restrict__ u,
                                               const float* __restrict__ ct,
                                               u16* __restrict__ o0,
                                               u16* __restrict__ o1,
                                               u16* __restrict__ o2,
                                               float* __restrict__ Bf) {
    int t4 = blockIdx.x * 256 + threadIdx.x;   // float4 index over p
    int i0 = blockIdx.y * 32;
    int z  = blockIdx.z; int proj = z >> 3; int f = z & 7;
    const float* wT   = proj == 0 ? w0 : (proj == 1 ? w1 : w2);
    const float* bias = proj == 0 ? b0 : (proj == 1 ? b1 : b2);
    u16*         out  = proj == 0 ? o0 : (proj == 1 ? o1 : o2);
    const float4* xp = (const float4*)(x + (size_t)f * C_ * P_) + t4;
    float4 acc[32];
#pragma unroll
    for (int ii = 0; ii < 32; ++ii) { acc[ii].x = 0.f; acc[ii].y = 0.f; acc[ii].z = 0.f; acc[ii].w = 0.f; }
    bool doBf = (proj == 2) && (blockIdx.y == 1);
    float4 accb; accb.x = accb.y = accb.z = accb.w = 0.f;
#pragma unroll 2
    for (int c = 0; c < C_; ++c) {
        float4 xv = xp[(size_t)c * (P_/4)];
        const float* wr = wT + (size_t)c * I_ + i0;   // uniform -> s_load
#pragma unroll
        for (int ii = 0; ii < 32; ++ii) {
            float w = wr[ii];
            acc[ii].x += xv.x * w; acc[ii].y += xv.y * w;
            acc[ii].z += xv.z * w; acc[ii].w += xv.w * w;
        }
        if (doBf) {
            float uv = u[c];
            accb.x += xv.x * uv; accb.y += xv.y * uv;
            accb.z += xv.z * uv; accb.w += xv.w * uv;
        }
    }
#pragma unroll
    for (int ii = 0; ii < 32; ++ii) {
        float bv = bias[i0 + ii];
        ushort4 r;
        r.x = f2b(acc[ii].x + bv); r.y = f2b(acc[ii].y + bv);
        r.z = f2b(acc[ii].z + bv); r.w = f2b(acc[ii].w + bv);
        ((ushort4*)(out + ((size_t)f * I_ + i0 + ii) * P_))[t4] = r;
    }
    if (doBf) {
        float c1 = ct[1];
        float4 r; r.x = accb.x + c1; r.y = accb.y + c1; r.z = accb.z + c1; r.w = accb.w + c1;
        ((float4*)(Bf + (size_t)f * P_))[t4] = r;
    }
}

// y<4: GR[i0..i0+16)[p] fp32 = conv(rgb, rgT) + rg_b;  y==4: SR[p] = ct0 + rgb.vt
__global__ __launch_bounds__(256) void k_rg(const float* __restrict__ rgb,
                                            const float* __restrict__ rgT,
                                            const float* __restrict__ rg_b,
                                            const float* __restrict__ vt,
                                            const float* __restrict__ ct,
                                            float* __restrict__ GR,
                                            float* __restrict__ SR) {
    int p = blockIdx.x * 256 + threadIdx.x;
    int y = blockIdx.y;
    if (y == 4) {
        float s = ct[0];
        for (int c = 0; c < C_; ++c) s += rgb[(size_t)c * P_ + p] * vt[c];
        SR[p] = s;
        return;
    }
    int i0 = y * 16;
    float acc[16];
#pragma unroll
    for (int ii = 0; ii < 16; ++ii) acc[ii] = 0.f;
#pragma unroll 2
    for (int c = 0; c < C_; ++c) {
        float xv = rgb[(size_t)c * P_ + p];
        const float* wr = rgT + (size_t)c * I_ + i0;
#pragma unroll
        for (int ii = 0; ii < 16; ++ii) acc[ii] += xv * wr[ii];
    }
#pragma unroll
    for (int ii = 0; ii < 16; ++ii) GR[(size_t)(i0 + ii) * P_ + p] = acc[ii] + rg_b[i0 + ii];
}

// scores: S[k][p][f1] (bf16) = exp(mask * sum_i PH[f1,i,p]*TH[f2(k),i,q_k])
// thread = 1px x 8f1 x 4k; stores are ushort8 coalesced (16B/lane contiguous)
__global__ __launch_bounds__(256) void k_scores(const u16* __restrict__ PH,
                                                const u16* __restrict__ TH,
                                                u16* __restrict__ S) {
    int p  = blockIdx.x * 256 + threadIdx.x;
    int k0 = blockIdx.y * 4;
    int px = p % W_, py = p / W_;
    size_t tb[4]; float msk[4];
#pragma unroll
    for (int kk = 0; kk < 4; ++kk) {
        int k  = k0 + kk;
        int f2 = k / T_;
        int t  = k - f2 * T_;
        int dy = DY[t], dx = DX[t];
        bool v = ((unsigned)(py + dy) < H_) && ((unsigned)(px + dx) < W_);
        int q  = p + dy * W_ + dx;
        q = min(max(q, 0), P_ - 1);
        tb[kk]  = (size_t)f2 * I_ * P_ + q;
        msk[kk] = v ? 1.f : 0.f;
    }
    float acc[8][4];
#pragma unroll
    for (int a = 0; a < 8; ++a)
#pragma unroll
        for (int b = 0; b < 4; ++b) acc[a][b] = 0.f;
#pragma unroll 2
    for (int i = 0; i < I_; ++i) {
        float phv[8];
#pragma unroll
        for (int f1 = 0; f1 < 8; ++f1) phv[f1] = b2f(PH[((size_t)f1 * I_ + i) * P_ + p]);
        float tv[4];
#pragma unroll
        for (int kk = 0; kk < 4; ++kk) tv[kk] = b2f(TH[tb[kk] + (size_t)i * P_]);
#pragma unroll
        for (int kk = 0; kk < 4; ++kk)
#pragma unroll
            for (int f1 = 0; f1 < 8; ++f1) acc[f1][kk] += phv[f1] * tv[kk];
    }
    // exp folded (|score| << 88); OOB -> exp(0)=1, matches reference denominator
#pragma unroll
    for (int kk = 0; kk < 4; ++kk) {
        u16x8 r;
#pragma unroll
        for (int f1 = 0; f1 < 8; ++f1) r[f1] = f2b(__expf(acc[f1][kk] * msk[kk]));
        *(u16x8*)(S + ((size_t)(k0 + kk) * P_ + p) * 8) = r;
    }
}

// k_y: partial over quarter of f2 (2 f2 each). thread = 1px x 8f1 x 8i, rolled loops.
// S layout [k][p][f1]: one coalesced ushort8 per tap. G gathers stay scalar [f][i][p].
// Yp[qtr][f1][p][i] bf16 (ushort8 stores); den partial by iblk==0.
__global__ __launch_bounds__(256) void k_y(const u16* __restrict__ S,
                                           const u16* __restrict__ G,
                                           u16* __restrict__ Yp,
                                           float* __restrict__ DEN) {
    int p   = blockIdx.x * 256 + threadIdx.x;
    int i0  = blockIdx.y * 8;
    int qtr = blockIdx.z;
    int px = p % W_, py = p / W_;
    float acc[8][8];
    float den[8];
#pragma unroll
    for (int a = 0; a < 8; ++a) {
        den[a] = 0.f;
#pragma unroll
        for (int b = 0; b < 8; ++b) acc[a][b] = 0.f;
    }
#pragma unroll 1
    for (int f2 = qtr * 2; f2 < qtr * 2 + 2; ++f2) {
        const u16* Gb = G + ((size_t)f2 * I_ + i0) * P_;
#pragma unroll 1
        for (int t = 0; t < T_; ++t) {
            int dy = CDY[t], dx = CDX[t], k = CK[t];
            bool v = ((unsigned)(py + dy) < H_) && ((unsigned)(px + dx) < W_);
            int q  = p + dy * W_ + dx;
            q = min(max(q, 0), P_ - 1);
            float mt = v ? 1.f : 0.f;
            u16x8 svv = *(const u16x8*)(S + ((size_t)(f2 * T_ + k) * P_ + p) * 8);
            float sv[8];
#pragma unroll
            for (int ff = 0; ff < 8; ++ff) sv[ff] = b2f(svv[ff]);
            float gv[8];
#pragma unroll
            for (int ii = 0; ii < 8; ++ii)
                gv[ii] = b2f(Gb[(size_t)ii * P_ + q]) * mt;
#pragma unroll
            for (int ff = 0; ff < 8; ++ff) {
                den[ff] += sv[ff];
#pragma unroll
                for (int ii = 0; ii < 8; ++ii)
                    acc[ff][ii] += sv[ff] * gv[ii];
            }
        }
    }
    if (blockIdx.y == 0) {
#pragma unroll
        for (int ff = 0; ff < 8; ++ff)
            DEN[(size_t)(qtr * F_ + ff) * P_ + p] = den[ff];
    }
    u16* Yh = Yp + (size_t)qtr * F_ * P_ * I_;
#pragma unroll
    for (int ff = 0; ff < 8; ++ff) {
        u16x8 r;
#pragma unroll
        for (int ii = 0; ii < 8; ++ii) r[ii] = f2b(acc[ff][ii]);
        *(u16x8*)(Yh + ((size_t)ff * P_ + p) * I_ + i0) = r;
    }
}

// Yr[f][p][i] bf16 = sum_t relu(SR[q]+Bf[f][p])/T * GR[i][q]; GR loads shared across 8 f
__global__ __launch_bounds__(128) void k_yr(const float* __restrict__ SR,
                                            const float* __restrict__ Bf,
                                            const float* __restrict__ GR,
                                            u16* __restrict__ Yr) {
    int p  = blockIdx.x * 128 + threadIdx.x;
    int i0 = blockIdx.y * 8;
    int px = p % W_, py = p / W_;
    float bfv[8];
#pragma unroll
    for (int f = 0; f < 8; ++f) bfv[f] = Bf[f * P_ + p];
    float acc[8][8];
#pragma unroll
    for (int a = 0; a < 8; ++a)
#pragma unroll
        for (int b = 0; b < 8; ++b) acc[a][b] = 0.f;
#pragma unroll
    for (int t = 0; t < T_; ++t) {
        int dy = DY[t], dx = DX[t];
        bool v = ((unsigned)(py + dy) < H_) && ((unsigned)(px + dx) < W_);
        int q  = p + dy * W_ + dx;
        q = min(max(q, 0), P_ - 1);
        float sr = SR[q];
        float gr[8];
#pragma unroll
        for (int ii = 0; ii < 8; ++ii) gr[ii] = GR[(size_t)(i0 + ii) * P_ + q];
#pragma unroll
        for (int f = 0; f < 8; ++f) {
            float fv = v ? fmaxf(sr + bfv[f], 0.f) * (1.f / (float)T_) : 0.f;
#pragma unroll
            for (int ii = 0; ii < 8; ++ii) acc[f][ii] += fv * gr[ii];
        }
    }
#pragma unroll
    for (int f = 0; f < 8; ++f) {
        u16x8 r;
#pragma unroll
        for (int ii = 0; ii < 8; ++ii) r[ii] = f2b(acc[f][ii]);
        *(u16x8*)(Yr + ((size_t)f * P_ + p) * I_ + i0) = r;
    }
}

// out[f][c][p] = (sum_i (sum_q Ypq)_i * WT[i][c]) / (sum_q DENq) + sum_i Yr_i * rWT[i][c]
//              + Wb[c] + rWb[c] + x;  32 c per thread, ushort8 Y loads (i-contiguous)
__global__ __launch_bounds__(256) void k_final(const u16* __restrict__ Yp,
                                               const u16* __restrict__ Yr,
                                               const float* __restrict__ DEN,
                                               const float* __restrict__ WT,
                                               const float* __restrict__ rWT,
                                               const float* __restrict__ Wb,
                                               const float* __restrict__ rWb,
                                               const float* __restrict__ x,
                                               float* __restrict__ out) {
    int p  = blockIdx.x * 256 + threadIdx.x;
    int f  = blockIdx.y;
    int c0 = blockIdx.z * 32;
    float dv = 1.f / (DEN[(size_t)f * P_ + p]
                    + DEN[(size_t)(F_ + f) * P_ + p]
                    + DEN[(size_t)(2 * F_ + f) * P_ + p]
                    + DEN[(size_t)(3 * F_ + f) * P_ + p]);
    float acc_y[32], acc_r[32];
#pragma unroll
    for (int cc = 0; cc < 32; ++cc) { acc_y[cc] = 0.f; acc_r[cc] = 0.f; }
    const size_t FPI = (size_t)F_ * P_ * I_;
    const u16* yb = Yp + ((size_t)f * P_ + p) * I_;
    const u16* yr = Yr + ((size_t)f * P_ + p) * I_;
#pragma unroll 2
    for (int i8 = 0; i8 < 8; ++i8) {
        u16x8 q0 = *(const u16x8*)(yb + i8 * 8);
        u16x8 q1 = *(const u16x8*)(yb + FPI + i8 * 8);
        u16x8 q2 = *(const u16x8*)(yb + 2 * FPI + i8 * 8);
        u16x8 q3 = *(const u16x8*)(yb + 3 * FPI + i8 * 8);
        u16x8 rv = *(const u16x8*)(yr + i8 * 8);
#pragma unroll
        for (int j = 0; j < 8; ++j) {
            float ys = b2f(q0[j]) + b2f(q1[j]) + b2f(q2[j]) + b2f(q3[j]);
            float yv = b2f(rv[j]);
            int i = i8 * 8 + j;
            const float* wr = WT  + (size_t)i * C_ + c0;   // uniform -> s_load
            const float* rw = rWT + (size_t)i * C_ + c0;
#pragma unroll
            for (int cc = 0; cc < 32; ++cc) {
                acc_y[cc] += ys * wr[cc];
                acc_r[cc] += yv * rw[cc];
            }
        }
    }
#pragma unroll
    for (int cc = 0; cc < 32; ++cc) {
        size_t o = ((size_t)f * C_ + c0 + cc) * P_ + p;
        out[o] = acc_y[cc] * dv + acc_r[cc] + x[o] + Wb[c0 + cc] + rWb[c0 + cc];
    }
}

extern "C" void kernel_launch(void* const* d_in, const int* in_sizes, int n_in,
                              void* d_out, int out_size, void* d_ws, size_t ws_size,
                              hipStream_t stream) {
    const float* x    = (const float*)d_in[0];
    const float* rgb  = (const float*)d_in[1];
    const float* g_w  = (const float*)d_in[2];
    const float* g_b  = (const float*)d_in[3];
    const float* th_w = (const float*)d_in[4];
    const float* th_b = (const float*)d_in[5];
    const float* ph_w = (const float*)d_in[6];
    const float* ph_b = (const float*)d_in[7];
    const float* W_w  = (const float*)d_in[8];
    const float* W_b  = (const float*)d_in[9];
    const float* rg_w = (const float*)d_in[10];
    const float* rg_b = (const float*)d_in[11];
    const float* rt_w = (const float*)d_in[12];
    const float* rt_b = (const float*)d_in[13];
    const float* rp_w = (const float*)d_in[14];
    const float* rp_b = (const float*)d_in[15];
    const float* rW_w = (const float*)d_in[16];
    const float* rW_b = (const float*)d_in[17];
    const float* cp_w = (const float*)d_in[18];
    float* out = (float*)d_out;

    const size_t FIP = (size_t)F_ * I_ * P_;   // 4718592
    const size_t SKP = (size_t)F_ * KK_ * P_;  // 10027008

    u16* Gb  = (u16*)d_ws;            // [f][i][p] bf16
    u16* THb = Gb  + FIP;             // [f][i][p] bf16
    u16* PHb = THb + FIP;             // [f][i][p] bf16
    u16* Sb  = PHb + FIP;             // [k][p][f1] bf16
    u16* Yp  = Sb  + SKP;             // [4][f][p][i] bf16
    u16* Yr  = Yp  + 4 * FIP;         // [f][p][i] bf16
    float* GR  = (float*)(Yr + FIP);  // [i][p] fp32
    float* SR  = GR + (size_t)I_ * P_;
    float* Bf  = SR + P_;
    float* DEN = Bf + (size_t)F_ * P_;        // [4][f][p]
    float* VT  = DEN + 4 * (size_t)F_ * P_;
    float* U   = VT + C_;
    float* CT  = U + C_;
    float* gT  = CT + 16;
    float* thT = gT  + (size_t)C_ * I_;
    float* phT = thT + (size_t)C_ * I_;
    float* rgT = phT + (size_t)C_ * I_;
    float* WT  = rgT + (size_t)C_ * I_;
    float* rWT = WT  + (size_t)C_ * I_;

    // weight prep
    k_prep<<<1, 128, 0, stream>>>(rt_w, rp_w, rt_b, rp_b, cp_w, VT, U, CT);
    k_tr<<<dim3(32, 6), 256, 0, stream>>>(g_w, th_w, ph_w, rg_w, W_w, rW_w,
                                          gT, thT, phT, rgT, WT, rWT);

    // projections of x -> bf16 (G, TH, PH) + Bf fold (i-block 32)
    k_conv3<<<dim3(P_ / 1024, 2, 24), 256, 0, stream>>>(x, gT, thT, phT,
                                                        g_b, th_b, ph_b, U, CT,
                                                        Gb, THb, PHb, Bf);

    // rgb-side: GR conv + SR field
    k_rg<<<dim3(P_ / 256, 5), 256, 0, stream>>>(rgb, rgT, rg_b, VT, CT, GR, SR);

    // attention scores (exp folded, bf16 out; S layout [k][p][f1])
    k_scores<<<dim3(P_ / 256, KK_ / 4), 256, 0, stream>>>(PHb, THb, Sb);

    // attention apply, f2 quarters -> bf16 partials [qtr][f][p][i] + den partials
    k_y<<<dim3(P_ / 256, I_ / 8, 4), 256, 0, stream>>>(Sb, Gb, Yp, DEN);

    // rgb-branch tap-sum over i (GR shared across f) -> Yr [f][p][i]
    k_yr<<<dim3(P_ / 128, I_ / 8), 128, 0, stream>>>(SR, Bf, GR, Yr);

    // final: combine partials, two uniform-weight convs, biases + residual (c-block 32)
    k_final<<<dim3(P_ / 256, F_, C_ / 32), 256, 0, stream>>>(Yp, Yr, DEN, WT, rWT,
                                                             W_b, rW_b, x, out);
}

// Round 11
// 278.731 us; speedup vs baseline: 1.2476x; 1.2476x over previous
//
#include <hip/hip_runtime.h>

#define F_ 8
#define C_ 128
#define H_ 96
#define W_ 96
#define P_ (H_*W_)   // 9216
#define I_ 64
#define T_ 17
#define KK_ (F_*T_)  // 136

// compile-time tap offsets (full unroll -> immediates) — used by k_scores / k_yr
__device__ constexpr int DY[T_] = {-1,-1,-1, 0,0,0, 1,1,1, -3,-3,-3, 0,0, 3,3,3};
__device__ constexpr int DX[T_] = {-1, 0, 1,-1,0,1,-1,0,1, -3, 0, 3,-3,3,-3,0,3};

// dy-grouped tap order for k_y (consecutive taps share cache lines; CK = original k)
__constant__ int CDY[T_] = {-3,-3,-3, -1,-1,-1,  0, 0,0,0, 0,  1,1,1,  3, 3, 3};
__constant__ int CDX[T_] = {-3, 0, 3, -1, 0, 1, -3,-1,0,1, 3, -1,0,1, -3, 0, 3};
__constant__ int CK [T_] = { 9,10,11,  0, 1, 2, 12, 3,4,5,13,  6,7,8, 14,15,16};

typedef unsigned short u16;
typedef u16 u16x8 __attribute__((ext_vector_type(8)));

__device__ __forceinline__ float b2f(u16 u) { return __uint_as_float(((unsigned)u) << 16); }
__device__ __forceinline__ u16 f2b(float f) {
    unsigned u = __float_as_uint(f);
    u += 0x7fff + ((u >> 16) & 1);   // RNE
    return (u16)(u >> 16);
}

// vt[c] = sum_i wt[i]*rtw[i,c]; u[c] = sum_i wp[i]*rpw[i,c]; ct[0]=wt.rtb; ct[1]=wp.rpb
__global__ __launch_bounds__(128) void k_prep(const float* __restrict__ rtw,
                                              const float* __restrict__ rpw,
                                              const float* __restrict__ rtb,
                                              const float* __restrict__ rpb,
                                              const float* __restrict__ cp,
                                              float* __restrict__ vt,
                                              float* __restrict__ u,
                                              float* __restrict__ ct) {
    int c = threadIdx.x;  // 128
    float a = 0.f, b2 = 0.f;
    for (int i = 0; i < I_; ++i) {
        a  += cp[i]      * rtw[i*C_ + c];
        b2 += cp[I_ + i] * rpw[i*C_ + c];
    }
    vt[c] = a; u[c] = b2;
    if (c == 0) { float s = 0.f; for (int i = 0; i < I_; ++i) s += cp[i]      * rtb[i]; ct[0] = s; }
    if (c == 1) { float s = 0.f; for (int i = 0; i < I_; ++i) s += cp[I_ + i] * rpb[i]; ct[1] = s; }
}

// 6 weight transposes: 0-3: [I,C]->[C][I] (g,th,ph,rg); 4-5: [C,I]->[I][C] (W,rW)
__global__ __launch_bounds__(256) void k_tr(const float* __restrict__ g_w,
                                            const float* __restrict__ th_w,
                                            const float* __restrict__ ph_w,
                                            const float* __restrict__ rg_w,
                                            const float* __restrict__ W_w,
                                            const float* __restrict__ rW_w,
                                            float* __restrict__ gT,
                                            float* __restrict__ thT,
                                            float* __restrict__ phT,
                                            float* __restrict__ rgT,
                                            float* __restrict__ WT,
                                            float* __restrict__ rWT) {
    int which = blockIdx.y;
    int idx = blockIdx.x * 256 + threadIdx.x;
    const float* src; float* dst; int Cc;
    if      (which == 0) { src = g_w;  dst = gT;  Cc = C_; }
    else if (which == 1) { src = th_w; dst = thT; Cc = C_; }
    else if (which == 2) { src = ph_w; dst = phT; Cc = C_; }
    else if (which == 3) { src = rg_w; dst = rgT; Cc = C_; }
    else if (which == 4) { src = W_w;  dst = WT;  Cc = I_; }
    else                 { src = rW_w; dst = rWT; Cc = I_; }
    int R = (C_*I_) / Cc;
    int r = idx / Cc, c2 = idx % Cc;
    dst[c2 * R + r] = src[idx];
}

// three convs on x -> bf16 [f][i][p]; 4px/thread via float4, 32 i per thread
// Folds Bf (fp32) into proj==2,y==1
__global__ __launch_bounds__(256) void k_conv3(const float* __restrict__ x,
                                               const float* __restrict__ w0,
                                               const float* __restrict__ w1,
                                               const float* __restrict__ w2,
                                               const float* __restrict__ b0,
                                               const float* __restrict__ b1,
                                               const float* __restrict__ b2,
                                               const float* __restrict__ u,
                                               const float* __restrict__ ct,
                                               u16* __restrict__ o0,
                                               u16* __restrict__ o1,
                                               u16* __restrict__ o2,
                                               float* __restrict__ Bf) {
    int t4 = blockIdx.x * 256 + threadIdx.x;   // float4 index over p
    int i0 = blockIdx.y * 32;
    int z  = blockIdx.z; int proj = z >> 3; int f = z & 7;
    const float* wT   = proj == 0 ? w0 : (proj == 1 ? w1 : w2);
    const float* bias = proj == 0 ? b0 : (proj == 1 ? b1 : b2);
    u16*         out  = proj == 0 ? o0 : (proj == 1 ? o1 : o2);
    const float4* xp = (const float4*)(x + (size_t)f * C_ * P_) + t4;
    float4 acc[32];
#pragma unroll
    for (int ii = 0; ii < 32; ++ii) { acc[ii].x = 0.f; acc[ii].y = 0.f; acc[ii].z = 0.f; acc[ii].w = 0.f; }
    bool doBf = (proj == 2) && (blockIdx.y == 1);
    float4 accb; accb.x = accb.y = accb.z = accb.w = 0.f;
#pragma unroll 2
    for (int c = 0; c < C_; ++c) {
        float4 xv = xp[(size_t)c * (P_/4)];
        const float* wr = wT + (size_t)c * I_ + i0;   // uniform -> s_load
#pragma unroll
        for (int ii = 0; ii < 32; ++ii) {
            float w = wr[ii];
            acc[ii].x += xv.x * w; acc[ii].y += xv.y * w;
            acc[ii].z += xv.z * w; acc[ii].w += xv.w * w;
        }
        if (doBf) {
            float uv = u[c];
            accb.x += xv.x * uv; accb.y += xv.y * uv;
            accb.z += xv.z * uv; accb.w += xv.w * uv;
        }
    }
#pragma unroll
    for (int ii = 0; ii < 32; ++ii) {
        float bv = bias[i0 + ii];
        ushort4 r;
        r.x = f2b(acc[ii].x + bv); r.y = f2b(acc[ii].y + bv);
        r.z = f2b(acc[ii].z + bv); r.w = f2b(acc[ii].w + bv);
        ((ushort4*)(out + ((size_t)f * I_ + i0 + ii) * P_))[t4] = r;
    }
    if (doBf) {
        float c1 = ct[1];
        float4 r; r.x = accb.x + c1; r.y = accb.y + c1; r.z = accb.z + c1; r.w = accb.w + c1;
        ((float4*)(Bf + (size_t)f * P_))[t4] = r;
    }
}

// y<4: GR[i0..i0+16)[p] fp32 = conv(rgb, rgT) + rg_b;  y==4: SR[p] = ct0 + rgb.vt
__global__ __launch_bounds__(256) void k_rg(const float* __restrict__ rgb,
                                            const float* __restrict__ rgT,
                                            const float* __restrict__ rg_b,
                                            const float* __restrict__ vt,
                                            const float* __restrict__ ct,
                                            float* __restrict__ GR,
                                            float* __restrict__ SR) {
    int p = blockIdx.x * 256 + threadIdx.x;
    int y = blockIdx.y;
    if (y == 4) {
        float s = ct[0];
        for (int c = 0; c < C_; ++c) s += rgb[(size_t)c * P_ + p] * vt[c];
        SR[p] = s;
        return;
    }
    int i0 = y * 16;
    float acc[16];
#pragma unroll
    for (int ii = 0; ii < 16; ++ii) acc[ii] = 0.f;
#pragma unroll 2
    for (int c = 0; c < C_; ++c) {
        float xv = rgb[(size_t)c * P_ + p];
        const float* wr = rgT + (size_t)c * I_ + i0;
#pragma unroll
        for (int ii = 0; ii < 16; ++ii) acc[ii] += xv * wr[ii];
    }
#pragma unroll
    for (int ii = 0; ii < 16; ++ii) GR[(size_t)(i0 + ii) * P_ + p] = acc[ii] + rg_b[i0 + ii];
}

// scores: S[k][p][f1] (bf16) = exp(mask * sum_i PH[f1,i,p]*TH[f2(k),i,q_k])
// thread = 1px x 8f1 x 4k; stores are ushort8 coalesced (16B/lane contiguous)
__global__ __launch_bounds__(256) void k_scores(const u16* __restrict__ PH,
                                                const u16* __restrict__ TH,
                                                u16* __restrict__ S) {
    int p  = blockIdx.x * 256 + threadIdx.x;
    int k0 = blockIdx.y * 4;
    int px = p % W_, py = p / W_;
    size_t tb[4]; float msk[4];
#pragma unroll
    for (int kk = 0; kk < 4; ++kk) {
        int k  = k0 + kk;
        int f2 = k / T_;
        int t  = k - f2 * T_;
        int dy = DY[t], dx = DX[t];
        bool v = ((unsigned)(py + dy) < H_) && ((unsigned)(px + dx) < W_);
        int q  = p + dy * W_ + dx;
        q = min(max(q, 0), P_ - 1);
        tb[kk]  = (size_t)f2 * I_ * P_ + q;
        msk[kk] = v ? 1.f : 0.f;
    }
    float acc[8][4];
#pragma unroll
    for (int a = 0; a < 8; ++a)
#pragma unroll
        for (int b = 0; b < 4; ++b) acc[a][b] = 0.f;
#pragma unroll 2
    for (int i = 0; i < I_; ++i) {
        float phv[8];
#pragma unroll
        for (int f1 = 0; f1 < 8; ++f1) phv[f1] = b2f(PH[((size_t)f1 * I_ + i) * P_ + p]);
        float tv[4];
#pragma unroll
        for (int kk = 0; kk < 4; ++kk) tv[kk] = b2f(TH[tb[kk] + (size_t)i * P_]);
#pragma unroll
        for (int kk = 0; kk < 4; ++kk)
#pragma unroll
            for (int f1 = 0; f1 < 8; ++f1) acc[f1][kk] += phv[f1] * tv[kk];
    }
    // exp folded (|score| << 88); OOB -> exp(0)=1, matches reference denominator
#pragma unroll
    for (int kk = 0; kk < 4; ++kk) {
        u16x8 r;
#pragma unroll
        for (int f1 = 0; f1 < 8; ++f1) r[f1] = f2b(__expf(acc[f1][kk] * msk[kk]));
        *(u16x8*)(S + ((size_t)(k0 + kk) * P_ + p) * 8) = r;
    }
}

// k_y: partial over quarter of f2 (2 f2 each). thread = 1px x 8f1 x 8i, rolled loops.
// S layout [k][p][f1]: one coalesced ushort8 per tap. G gathers stay scalar [f][i][p].
// Yp[qtr][f][ib][p][8i] bf16: interleaved-block layout -> lane-stride-16B ushort8 stores.
__global__ __launch_bounds__(256) void k_y(const u16* __restrict__ S,
                                           const u16* __restrict__ G,
                                           u16* __restrict__ Yp,
                                           float* __restrict__ DEN) {
    int p   = blockIdx.x * 256 + threadIdx.x;
    int ib  = blockIdx.y;           // i-block: i = ib*8 + ii
    int i0  = ib * 8;
    int qtr = blockIdx.z;
    int px = p % W_, py = p / W_;
    float acc[8][8];
    float den[8];
#pragma unroll
    for (int a = 0; a < 8; ++a) {
        den[a] = 0.f;
#pragma unroll
        for (int b = 0; b < 8; ++b) acc[a][b] = 0.f;
    }
#pragma unroll 1
    for (int f2 = qtr * 2; f2 < qtr * 2 + 2; ++f2) {
        const u16* Gb = G + ((size_t)f2 * I_ + i0) * P_;
#pragma unroll 1
        for (int t = 0; t < T_; ++t) {
            int dy = CDY[t], dx = CDX[t], k = CK[t];
            bool v = ((unsigned)(py + dy) < H_) && ((unsigned)(px + dx) < W_);
            int q  = p + dy * W_ + dx;
            q = min(max(q, 0), P_ - 1);
            float mt = v ? 1.f : 0.f;
            u16x8 svv = *(const u16x8*)(S + ((size_t)(f2 * T_ + k) * P_ + p) * 8);
            float sv[8];
#pragma unroll
            for (int ff = 0; ff < 8; ++ff) sv[ff] = b2f(svv[ff]);
            float gv[8];
#pragma unroll
            for (int ii = 0; ii < 8; ++ii)
                gv[ii] = b2f(Gb[(size_t)ii * P_ + q]) * mt;
#pragma unroll
            for (int ff = 0; ff < 8; ++ff) {
                den[ff] += sv[ff];
#pragma unroll
                for (int ii = 0; ii < 8; ++ii)
                    acc[ff][ii] += sv[ff] * gv[ii];
            }
        }
    }
    if (blockIdx.y == 0) {
#pragma unroll
        for (int ff = 0; ff < 8; ++ff)
            DEN[(size_t)(qtr * F_ + ff) * P_ + p] = den[ff];
    }
    u16* Yh = Yp + (size_t)qtr * F_ * P_ * I_;
#pragma unroll
    for (int ff = 0; ff < 8; ++ff) {
        u16x8 r;
#pragma unroll
        for (int ii = 0; ii < 8; ++ii) r[ii] = f2b(acc[ff][ii]);
        *(u16x8*)(Yh + (((size_t)ff * 8 + ib) * P_ + p) * 8) = r;
    }
}

// Yr[f][ib][p][8i] bf16 = sum_t relu(SR[q]+Bf[f][p])/T * GR[i][q]
__global__ __launch_bounds__(128) void k_yr(const float* __restrict__ SR,
                                            const float* __restrict__ Bf,
                                            const float* __restrict__ GR,
                                            u16* __restrict__ Yr) {
    int p  = blockIdx.x * 128 + threadIdx.x;
    int ib = blockIdx.y;
    int i0 = ib * 8;
    int px = p % W_, py = p / W_;
    float bfv[8];
#pragma unroll
    for (int f = 0; f < 8; ++f) bfv[f] = Bf[f * P_ + p];
    float acc[8][8];
#pragma unroll
    for (int a = 0; a < 8; ++a)
#pragma unroll
        for (int b = 0; b < 8; ++b) acc[a][b] = 0.f;
#pragma unroll
    for (int t = 0; t < T_; ++t) {
        int dy = DY[t], dx = DX[t];
        bool v = ((unsigned)(py + dy) < H_) && ((unsigned)(px + dx) < W_);
        int q  = p + dy * W_ + dx;
        q = min(max(q, 0), P_ - 1);
        float sr = SR[q];
        float gr[8];
#pragma unroll
        for (int ii = 0; ii < 8; ++ii) gr[ii] = GR[(size_t)(i0 + ii) * P_ + q];
#pragma unroll
        for (int f = 0; f < 8; ++f) {
            float fv = v ? fmaxf(sr + bfv[f], 0.f) * (1.f / (float)T_) : 0.f;
#pragma unroll
            for (int ii = 0; ii < 8; ++ii) acc[f][ii] += fv * gr[ii];
        }
    }
#pragma unroll
    for (int f = 0; f < 8; ++f) {
        u16x8 r;
#pragma unroll
        for (int ii = 0; ii < 8; ++ii) r[ii] = f2b(acc[f][ii]);
        *(u16x8*)(Yr + (((size_t)f * 8 + ib) * P_ + p) * 8) = r;
    }
}

// out[f][c][p] = (sum_i (sum_q Ypq)_i * WT[i][c]) / (sum_q DENq) + sum_i Yr_i * rWT[i][c]
//              + Wb[c] + rWb[c] + x;  32 c per thread
// Y loads: interleaved-block layout -> ushort8 with 16B lane stride (fully dense)
__global__ __launch_bounds__(256) void k_final(const u16* __restrict__ Yp,
                                               const u16* __restrict__ Yr,
                                               const float* __restrict__ DEN,
                                               const float* __restrict__ WT,
                                               const float* __restrict__ rWT,
                                               const float* __restrict__ Wb,
                                               const float* __restrict__ rWb,
                                               const float* __restrict__ x,
                                               float* __restrict__ out) {
    int p  = blockIdx.x * 256 + threadIdx.x;
    int f  = blockIdx.y;
    int c0 = blockIdx.z * 32;
    float dv = 1.f / (DEN[(size_t)f * P_ + p]
                    + DEN[(size_t)(F_ + f) * P_ + p]
                    + DEN[(size_t)(2 * F_ + f) * P_ + p]
                    + DEN[(size_t)(3 * F_ + f) * P_ + p]);
    float acc_y[32], acc_r[32];
#pragma unroll
    for (int cc = 0; cc < 32; ++cc) { acc_y[cc] = 0.f; acc_r[cc] = 0.f; }
    const size_t FPI = (size_t)F_ * P_ * I_;
#pragma unroll 2
    for (int i8 = 0; i8 < 8; ++i8) {
        size_t base = (((size_t)f * 8 + i8) * P_ + p) * 8;
        u16x8 q0 = *(const u16x8*)(Yp + base);
        u16x8 q1 = *(const u16x8*)(Yp + FPI + base);
        u16x8 q2 = *(const u16x8*)(Yp + 2 * FPI + base);
        u16x8 q3 = *(const u16x8*)(Yp + 3 * FPI + base);
        u16x8 rv = *(const u16x8*)(Yr + base);
#pragma unroll
        for (int j = 0; j < 8; ++j) {
            float ys = b2f(q0[j]) + b2f(q1[j]) + b2f(q2[j]) + b2f(q3[j]);
            float yv = b2f(rv[j]);
            int i = i8 * 8 + j;
            const float* wr = WT  + (size_t)i * C_ + c0;   // uniform -> s_load
            const float* rw = rWT + (size_t)i * C_ + c0;
#pragma unroll
            for (int cc = 0; cc < 32; ++cc) {
                acc_y[cc] += ys * wr[cc];
                acc_r[cc] += yv * rw[cc];
            }
        }
    }
#pragma unroll
    for (int cc = 0; cc < 32; ++cc) {
        size_t o = ((size_t)f * C_ + c0 + cc) * P_ + p;
        out[o] = acc_y[cc] * dv + acc_r[cc] + x[o] + Wb[c0 + cc] + rWb[c0 + cc];
    }
}

extern "C" void kernel_launch(void* const* d_in, const int* in_sizes, int n_in,
                              void* d_out, int out_size, void* d_ws, size_t ws_size,
                              hipStream_t stream) {
    const float* x    = (const float*)d_in[0];
    const float* rgb  = (const float*)d_in[1];
    const float* g_w  = (const float*)d_in[2];
    const float* g_b  = (const float*)d_in[3];
    const float* th_w = (const float*)d_in[4];
    const float* th_b = (const float*)d_in[5];
    const float* ph_w = (const float*)d_in[6];
    const float* ph_b = (const float*)d_in[7];
    const float* W_w  = (const float*)d_in[8];
    const float* W_b  = (const float*)d_in[9];
    const float* rg_w = (const float*)d_in[10];
    const float* rg_b = (const float*)d_in[11];
    const float* rt_w = (const float*)d_in[12];
    const float* rt_b = (const float*)d_in[13];
    const float* rp_w = (const float*)d_in[14];
    const float* rp_b = (const float*)d_in[15];
    const float* rW_w = (const float*)d_in[16];
    const float* rW_b = (const float*)d_in[17];
    const float* cp_w = (const float*)d_in[18];
    float* out = (float*)d_out;

    const size_t FIP = (size_t)F_ * I_ * P_;   // 4718592
    const size_t SKP = (size_t)F_ * KK_ * P_;  // 10027008

    u16* Gb  = (u16*)d_ws;            // [f][i][p] bf16
    u16* THb = Gb  + FIP;             // [f][i][p] bf16
    u16* PHb = THb + FIP;             // [f][i][p] bf16
    u16* Sb  = PHb + FIP;             // [k][p][f1] bf16
    u16* Yp  = Sb  + SKP;             // [4][f][ib][p][8] bf16
    u16* Yr  = Yp  + 4 * FIP;         // [f][ib][p][8] bf16
    float* GR  = (float*)(Yr + FIP);  // [i][p] fp32
    float* SR  = GR + (size_t)I_ * P_;
    float* Bf  = SR + P_;
    float* DEN = Bf + (size_t)F_ * P_;        // [4][f][p]
    float* VT  = DEN + 4 * (size_t)F_ * P_;
    float* U   = VT + C_;
    float* CT  = U + C_;
    float* gT  = CT + 16;
    float* thT = gT  + (size_t)C_ * I_;
    float* phT = thT + (size_t)C_ * I_;
    float* rgT = phT + (size_t)C_ * I_;
    float* WT  = rgT + (size_t)C_ * I_;
    float* rWT = WT  + (size_t)C_ * I_;

    // weight prep
    k_prep<<<1, 128, 0, stream>>>(rt_w, rp_w, rt_b, rp_b, cp_w, VT, U, CT);
    k_tr<<<dim3(32, 6), 256, 0, stream>>>(g_w, th_w, ph_w, rg_w, W_w, rW_w,
                                          gT, thT, phT, rgT, WT, rWT);

    // projections of x -> bf16 (G, TH, PH) + Bf fold (i-block 32)
    k_conv3<<<dim3(P_ / 1024, 2, 24), 256, 0, stream>>>(x, gT, thT, phT,
                                                        g_b, th_b, ph_b, U, CT,
                                                        Gb, THb, PHb, Bf);

    // rgb-side: GR conv + SR field
    k_rg<<<dim3(P_ / 256, 5), 256, 0, stream>>>(rgb, rgT, rg_b, VT, CT, GR, SR);

    // attention scores (exp folded, bf16 out; S layout [k][p][f1])
    k_scores<<<dim3(P_ / 256, KK_ / 4), 256, 0, stream>>>(PHb, THb, Sb);

    // attention apply, f2 quarters -> bf16 partials [qtr][f][ib][p][8] + den partials
    k_y<<<dim3(P_ / 256, I_ / 8, 4), 256, 0, stream>>>(Sb, Gb, Yp, DEN);

    // rgb-branch tap-sum over i (GR shared across f) -> Yr [f][ib][p][8]
    k_yr<<<dim3(P_ / 128, I_ / 8), 128, 0, stream>>>(SR, Bf, GR, Yr);

    // final: combine partials, two uniform-weight convs, biases + residual (c-block 32)
    k_final<<<dim3(P_ / 256, F_, C_ / 32), 256, 0, stream>>>(Yp, Yr, DEN, WT, rWT,
                                                             W_b, rW_b, x, out);
}

// Round 12
// 260.950 us; speedup vs baseline: 1.3326x; 1.0681x over previous
//
#include <hip/hip_runtime.h>

#define F_ 8
#define C_ 128
#define H_ 96
#define W_ 96
#define P_ (H_*W_)   // 9216
#define I_ 64
#define I2_ (I_/2)   // 32 i-pairs
#define T_ 17
#define KK_ (F_*T_)  // 136

// compile-time tap offsets (full unroll -> immediates) — used by k_scores / k_yr
__device__ constexpr int DY[T_] = {-1,-1,-1, 0,0,0, 1,1,1, -3,-3,-3, 0,0, 3,3,3};
__device__ constexpr int DX[T_] = {-1, 0, 1,-1,0,1,-1,0,1, -3, 0, 3,-3,3,-3,0,3};

// dy-grouped tap order for k_y (consecutive taps share cache lines; CK = original k)
__constant__ int CDY[T_] = {-3,-3,-3, -1,-1,-1,  0, 0,0,0, 0,  1,1,1,  3, 3, 3};
__constant__ int CDX[T_] = {-3, 0, 3, -1, 0, 1, -3,-1,0,1, 3, -1,0,1, -3, 0, 3};
__constant__ int CK [T_] = { 9,10,11,  0, 1, 2, 12, 3,4,5,13,  6,7,8, 14,15,16};

typedef unsigned short u16;
typedef u16 u16x8 __attribute__((ext_vector_type(8)));
typedef float f32x2 __attribute__((ext_vector_type(2)));

__device__ __forceinline__ float b2f(u16 u) { return __uint_as_float(((unsigned)u) << 16); }
__device__ __forceinline__ float pairLo(unsigned v) { return __uint_as_float(v << 16); }
__device__ __forceinline__ float pairHi(unsigned v) { return __uint_as_float(v & 0xffff0000u); }
__device__ __forceinline__ u16 f2b(float f) {
    unsigned u = __float_as_uint(f);
    u += 0x7fff + ((u >> 16) & 1);   // RNE
    return (u16)(u >> 16);
}

// vt[c] = sum_i wt[i]*rtw[i,c]; u[c] = sum_i wp[i]*rpw[i,c]; ct[0]=wt.rtb; ct[1]=wp.rpb
__global__ __launch_bounds__(128) void k_prep(const float* __restrict__ rtw,
                                              const float* __restrict__ rpw,
                                              const float* __restrict__ rtb,
                                              const float* __restrict__ rpb,
                                              const float* __restrict__ cp,
                                              float* __restrict__ vt,
                                              float* __restrict__ u,
                                              float* __restrict__ ct) {
    int c = threadIdx.x;  // 128
    float a = 0.f, b2 = 0.f;
    for (int i = 0; i < I_; ++i) {
        a  += cp[i]      * rtw[i*C_ + c];
        b2 += cp[I_ + i] * rpw[i*C_ + c];
    }
    vt[c] = a; u[c] = b2;
    if (c == 0) { float s = 0.f; for (int i = 0; i < I_; ++i) s += cp[i]      * rtb[i]; ct[0] = s; }
    if (c == 1) { float s = 0.f; for (int i = 0; i < I_; ++i) s += cp[I_ + i] * rpb[i]; ct[1] = s; }
}

// 6 weight transposes: 0-3: [I,C]->[C][I] (g,th,ph,rg); 4-5: [C,I]->[I][C] (W,rW)
__global__ __launch_bounds__(256) void k_tr(const float* __restrict__ g_w,
                                            const float* __restrict__ th_w,
                                            const float* __restrict__ ph_w,
                                            const float* __restrict__ rg_w,
                                            const float* __restrict__ W_w,
                                            const float* __restrict__ rW_w,
                                            float* __restrict__ gT,
                                            float* __restrict__ thT,
                                            float* __restrict__ phT,
                                            float* __restrict__ rgT,
                                            float* __restrict__ WT,
                                            float* __restrict__ rWT) {
    int which = blockIdx.y;
    int idx = blockIdx.x * 256 + threadIdx.x;
    const float* src; float* dst; int Cc;
    if      (which == 0) { src = g_w;  dst = gT;  Cc = C_; }
    else if (which == 1) { src = th_w; dst = thT; Cc = C_; }
    else if (which == 2) { src = ph_w; dst = phT; Cc = C_; }
    else if (which == 3) { src = rg_w; dst = rgT; Cc = C_; }
    else if (which == 4) { src = W_w;  dst = WT;  Cc = I_; }
    else                 { src = rW_w; dst = rWT; Cc = I_; }
    int R = (C_*I_) / Cc;
    int r = idx / Cc, c2 = idx % Cc;
    dst[c2 * R + r] = src[idx];
}

// three convs on x -> bf16 i-pair-packed [f][i2][p][2i]; 4px/thread, 32 i per thread
// Folds Bf (fp32) into proj==2,y==1
__global__ __launch_bounds__(256) void k_conv3(const float* __restrict__ x,
                                               const float* __restrict__ w0,
                                               const float* __restrict__ w1,
                                               const float* __restrict__ w2,
                                               const float* __restrict__ b0,
                                               const float* __restrict__ b1,
                                               const float* __restrict__ b2,
                                               const float* __restrict__ u,
                                               const float* __restrict__ ct,
                                               u16* __restrict__ o0,
                                               u16* __restrict__ o1,
                                               u16* __restrict__ o2,
                                               float* __restrict__ Bf) {
    int t4 = blockIdx.x * 256 + threadIdx.x;   // float4 index over p
    int i0 = blockIdx.y * 32;
    int z  = blockIdx.z; int proj = z >> 3; int f = z & 7;
    const float* wT   = proj == 0 ? w0 : (proj == 1 ? w1 : w2);
    const float* bias = proj == 0 ? b0 : (proj == 1 ? b1 : b2);
    u16*         out  = proj == 0 ? o0 : (proj == 1 ? o1 : o2);
    const float4* xp = (const float4*)(x + (size_t)f * C_ * P_) + t4;
    float4 acc[32];
#pragma unroll
    for (int ii = 0; ii < 32; ++ii) { acc[ii].x = 0.f; acc[ii].y = 0.f; acc[ii].z = 0.f; acc[ii].w = 0.f; }
    bool doBf = (proj == 2) && (blockIdx.y == 1);
    float4 accb; accb.x = accb.y = accb.z = accb.w = 0.f;
#pragma unroll 2
    for (int c = 0; c < C_; ++c) {
        float4 xv = xp[(size_t)c * (P_/4)];
        const float* wr = wT + (size_t)c * I_ + i0;   // uniform -> s_load
#pragma unroll
        for (int ii = 0; ii < 32; ++ii) {
            float w = wr[ii];
            acc[ii].x += xv.x * w; acc[ii].y += xv.y * w;
            acc[ii].z += xv.z * w; acc[ii].w += xv.w * w;
        }
        if (doBf) {
            float uv = u[c];
            accb.x += xv.x * uv; accb.y += xv.y * uv;
            accb.z += xv.z * uv; accb.w += xv.w * uv;
        }
    }
    // store i-pair packed: [f][i2][p][2]; per i2, 4px*2i = one ushort8 (16B dense)
#pragma unroll
    for (int jj = 0; jj < 16; ++jj) {
        int iA = 2 * jj, iB = 2 * jj + 1;
        float bA = bias[i0 + iA], bB = bias[i0 + iB];
        u16x8 r;
        r[0] = f2b(acc[iA].x + bA); r[1] = f2b(acc[iB].x + bB);
        r[2] = f2b(acc[iA].y + bA); r[3] = f2b(acc[iB].y + bB);
        r[4] = f2b(acc[iA].z + bA); r[5] = f2b(acc[iB].z + bB);
        r[6] = f2b(acc[iA].w + bA); r[7] = f2b(acc[iB].w + bB);
        int i2 = (i0 >> 1) + jj;
        *(u16x8*)(out + (((size_t)f * I2_ + i2) * P_ + 4 * t4) * 2) = r;
    }
    if (doBf) {
        float c1 = ct[1];
        float4 r; r.x = accb.x + c1; r.y = accb.y + c1; r.z = accb.z + c1; r.w = accb.w + c1;
        ((float4*)(Bf + (size_t)f * P_))[t4] = r;
    }
}

// y<4: GR[i0..i0+16)[p] fp32 = conv(rgb, rgT) + rg_b;  y==4: SR[p] = ct0 + rgb.vt
__global__ __launch_bounds__(256) void k_rg(const float* __restrict__ rgb,
                                            const float* __restrict__ rgT,
                                            const float* __restrict__ rg_b,
                                            const float* __restrict__ vt,
                                            const float* __restrict__ ct,
                                            float* __restrict__ GR,
                                            float* __restrict__ SR) {
    int p = blockIdx.x * 256 + threadIdx.x;
    int y = blockIdx.y;
    if (y == 4) {
        float s = ct[0];
        for (int c = 0; c < C_; ++c) s += rgb[(size_t)c * P_ + p] * vt[c];
        SR[p] = s;
        return;
    }
    int i0 = y * 16;
    float acc[16];
#pragma unroll
    for (int ii = 0; ii < 16; ++ii) acc[ii] = 0.f;
#pragma unroll 2
    for (int c = 0; c < C_; ++c) {
        float xv = rgb[(size_t)c * P_ + p];
        const float* wr = rgT + (size_t)c * I_ + i0;
#pragma unroll
        for (int ii = 0; ii < 16; ++ii) acc[ii] += xv * wr[ii];
    }
#pragma unroll
    for (int ii = 0; ii < 16; ++ii) GR[(size_t)(i0 + ii) * P_ + p] = acc[ii] + rg_b[i0 + ii];
}

// scores: S[k][p][f1] (bf16) = exp(mask * sum_i PH[f1,i,p]*TH[f2(k),i,q_k])
// i-pair packed inputs: per i2-iter 8 PH uints + 4 TH uints -> 64 FMA
__global__ __launch_bounds__(256) void k_scores(const u16* __restrict__ PH,
                                                const u16* __restrict__ TH,
                                                u16* __restrict__ S) {
    int p  = blockIdx.x * 256 + threadIdx.x;
    int k0 = blockIdx.y * 4;
    int px = p % W_, py = p / W_;
    const unsigned* PHu = (const unsigned*)PH;
    const unsigned* THu = (const unsigned*)TH;
    size_t tb[4]; float msk[4];
#pragma unroll
    for (int kk = 0; kk < 4; ++kk) {
        int k  = k0 + kk;
        int f2 = k / T_;
        int t  = k - f2 * T_;
        int dy = DY[t], dx = DX[t];
        bool v = ((unsigned)(py + dy) < H_) && ((unsigned)(px + dx) < W_);
        int q  = p + dy * W_ + dx;
        q = min(max(q, 0), P_ - 1);
        tb[kk]  = (size_t)f2 * I2_ * P_ + q;   // uint index
        msk[kk] = v ? 1.f : 0.f;
    }
    float acc[8][4];
#pragma unroll
    for (int a = 0; a < 8; ++a)
#pragma unroll
        for (int b = 0; b < 4; ++b) acc[a][b] = 0.f;
#pragma unroll 2
    for (int i2 = 0; i2 < I2_; ++i2) {
        float phE[8], phO[8];
#pragma unroll
        for (int f1 = 0; f1 < 8; ++f1) {
            unsigned v = PHu[((size_t)f1 * I2_ + i2) * P_ + p];
            phE[f1] = pairLo(v); phO[f1] = pairHi(v);
        }
        float tvE[4], tvO[4];
#pragma unroll
        for (int kk = 0; kk < 4; ++kk) {
            unsigned v = THu[tb[kk] + (size_t)i2 * P_];
            tvE[kk] = pairLo(v); tvO[kk] = pairHi(v);
        }
#pragma unroll
        for (int kk = 0; kk < 4; ++kk)
#pragma unroll
            for (int f1 = 0; f1 < 8; ++f1)
                acc[f1][kk] += phE[f1] * tvE[kk] + phO[f1] * tvO[kk];
    }
    // exp folded (|score| << 88); OOB -> exp(0)=1, matches reference denominator
#pragma unroll
    for (int kk = 0; kk < 4; ++kk) {
        u16x8 r;
#pragma unroll
        for (int f1 = 0; f1 < 8; ++f1) r[f1] = f2b(__expf(acc[f1][kk] * msk[kk]));
        *(u16x8*)(S + ((size_t)(k0 + kk) * P_ + p) * 8) = r;
    }
}

// k_y: partial over quarter of f2 (2 f2 each). thread = 1px x 8f1 x 8i, rolled loops.
// S [k][p][f1]: one ushort8 per tap. G i-pair packed: 4 uint gathers per tap.
// Yp[qtr][f][ib][p][8i] bf16 (16B-dense stores); den partial by iblk==0.
__global__ __launch_bounds__(256) void k_y(const u16* __restrict__ S,
                                           const u16* __restrict__ G,
                                           u16* __restrict__ Yp,
                                           float* __restrict__ DEN) {
    int p   = blockIdx.x * 256 + threadIdx.x;
    int ib  = blockIdx.y;           // i-block: i = ib*8 + ii
    int qtr = blockIdx.z;
    int px = p % W_, py = p / W_;
    const unsigned* Gu = (const unsigned*)G;
    float acc[8][8];
    float den[8];
#pragma unroll
    for (int a = 0; a < 8; ++a) {
        den[a] = 0.f;
#pragma unroll
        for (int b = 0; b < 8; ++b) acc[a][b] = 0.f;
    }
#pragma unroll 1
    for (int f2 = qtr * 2; f2 < qtr * 2 + 2; ++f2) {
        const unsigned* Gb = Gu + ((size_t)f2 * I2_ + ib * 4) * P_;
#pragma unroll 1
        for (int t = 0; t < T_; ++t) {
            int dy = CDY[t], dx = CDX[t], k = CK[t];
            bool v = ((unsigned)(py + dy) < H_) && ((unsigned)(px + dx) < W_);
            int q  = p + dy * W_ + dx;
            q = min(max(q, 0), P_ - 1);
            float mt = v ? 1.f : 0.f;
            u16x8 svv = *(const u16x8*)(S + ((size_t)(f2 * T_ + k) * P_ + p) * 8);
            float sv[8];
#pragma unroll
            for (int ff = 0; ff < 8; ++ff) sv[ff] = b2f(svv[ff]);
            float gv[8];
#pragma unroll
            for (int jj = 0; jj < 4; ++jj) {
                unsigned gvv = Gb[(size_t)jj * P_ + q];
                gv[2*jj]   = pairLo(gvv) * mt;
                gv[2*jj+1] = pairHi(gvv) * mt;
            }
#pragma unroll
            for (int ff = 0; ff < 8; ++ff) {
                den[ff] += sv[ff];
#pragma unroll
                for (int ii = 0; ii < 8; ++ii)
                    acc[ff][ii] += sv[ff] * gv[ii];
            }
        }
    }
    if (blockIdx.y == 0) {
#pragma unroll
        for (int ff = 0; ff < 8; ++ff)
            DEN[(size_t)(qtr * F_ + ff) * P_ + p] = den[ff];
    }
    u16* Yh = Yp + (size_t)qtr * F_ * P_ * I_;
#pragma unroll
    for (int ff = 0; ff < 8; ++ff) {
        u16x8 r;
#pragma unroll
        for (int ii = 0; ii < 8; ++ii) r[ii] = f2b(acc[ff][ii]);
        *(u16x8*)(Yh + (((size_t)ff * 8 + ib) * P_ + p) * 8) = r;
    }
}

// Yr[f][ib][p][8i] bf16 = sum_t relu(SR[q]+Bf[f][p])/T * GR[i][q]
__global__ __launch_bounds__(128) void k_yr(const float* __restrict__ SR,
                                            const float* __restrict__ Bf,
                                            const float* __restrict__ GR,
                                            u16* __restrict__ Yr) {
    int p  = blockIdx.x * 128 + threadIdx.x;
    int ib = blockIdx.y;
    int i0 = ib * 8;
    int px = p % W_, py = p / W_;
    float bfv[8];
#pragma unroll
    for (int f = 0; f < 8; ++f) bfv[f] = Bf[f * P_ + p];
    float acc[8][8];
#pragma unroll
    for (int a = 0; a < 8; ++a)
#pragma unroll
        for (int b = 0; b < 8; ++b) acc[a][b] = 0.f;
#pragma unroll
    for (int t = 0; t < T_; ++t) {
        int dy = DY[t], dx = DX[t];
        bool v = ((unsigned)(py + dy) < H_) && ((unsigned)(px + dx) < W_);
        int q  = p + dy * W_ + dx;
        q = min(max(q, 0), P_ - 1);
        float sr = SR[q];
        float gr[8];
#pragma unroll
        for (int ii = 0; ii < 8; ++ii) gr[ii] = GR[(size_t)(i0 + ii) * P_ + q];
#pragma unroll
        for (int f = 0; f < 8; ++f) {
            float fv = v ? fmaxf(sr + bfv[f], 0.f) * (1.f / (float)T_) : 0.f;
#pragma unroll
            for (int ii = 0; ii < 8; ++ii) acc[f][ii] += fv * gr[ii];
        }
    }
#pragma unroll
    for (int f = 0; f < 8; ++f) {
        u16x8 r;
#pragma unroll
        for (int ii = 0; ii < 8; ++ii) r[ii] = f2b(acc[f][ii]);
        *(u16x8*)(Yr + (((size_t)f * 8 + ib) * P_ + p) * 8) = r;
    }
}

// out[f][c][p] = (sum_i (sum_q Ypq)_i * WT[i][c]) / (sum_q DENq) + sum_i Yr_i * rWT[i][c]
//              + Wb[c] + rWb[c] + x;  32 c per thread, packed f32x2 FMA (v_pk_fma_f32)
__global__ __launch_bounds__(256) void k_final(const u16* __restrict__ Yp,
                                               const u16* __restrict__ Yr,
                                               const float* __restrict__ DEN,
                                               const float* __restrict__ WT,
                                               const float* __restrict__ rWT,
                                               const float* __restrict__ Wb,
                                               const float* __restrict__ rWb,
                                               const float* __restrict__ x,
                                               float* __restrict__ out) {
    int p  = blockIdx.x * 256 + threadIdx.x;
    int f  = blockIdx.y;
    int c0 = blockIdx.z * 32;
    float dv = 1.f / (DEN[(size_t)f * P_ + p]
                    + DEN[(size_t)(F_ + f) * P_ + p]
                    + DEN[(size_t)(2 * F_ + f) * P_ + p]
                    + DEN[(size_t)(3 * F_ + f) * P_ + p]);
    f32x2 acc_y[16], acc_r[16];
#pragma unroll
    for (int cc = 0; cc < 16; ++cc) { acc_y[cc] = 0.f; acc_r[cc] = 0.f; }
    const size_t FPI = (size_t)F_ * P_ * I_;
#pragma unroll 2
    for (int i8 = 0; i8 < 8; ++i8) {
        size_t base = (((size_t)f * 8 + i8) * P_ + p) * 8;
        u16x8 q0 = *(const u16x8*)(Yp + base);
        u16x8 q1 = *(const u16x8*)(Yp + FPI + base);
        u16x8 q2 = *(const u16x8*)(Yp + 2 * FPI + base);
        u16x8 q3 = *(const u16x8*)(Yp + 3 * FPI + base);
        u16x8 rv = *(const u16x8*)(Yr + base);
#pragma unroll
        for (int j = 0; j < 8; ++j) {
            float ys = b2f(q0[j]) + b2f(q1[j]) + b2f(q2[j]) + b2f(q3[j]);
            float yv = b2f(rv[j]);
            f32x2 ys2; ys2[0] = ys; ys2[1] = ys;
            f32x2 yv2; yv2[0] = yv; yv2[1] = yv;
            int i = i8 * 8 + j;
            const f32x2* wr = (const f32x2*)(WT  + (size_t)i * C_ + c0);
            const f32x2* rw = (const f32x2*)(rWT + (size_t)i * C_ + c0);
#pragma unroll
            for (int cc = 0; cc < 16; ++cc) {
                acc_y[cc] += ys2 * wr[cc];   // v_pk_fma_f32
                acc_r[cc] += yv2 * rw[cc];
            }
        }
    }
#pragma unroll
    for (int cc = 0; cc < 16; ++cc) {
#pragma unroll
        for (int h = 0; h < 2; ++h) {
            int c = c0 + 2 * cc + h;
            size_t o = ((size_t)f * C_ + c) * P_ + p;
            out[o] = acc_y[cc][h] * dv + acc_r[cc][h] + x[o] + Wb[c] + rWb[c];
        }
    }
}

extern "C" void kernel_launch(void* const* d_in, const int* in_sizes, int n_in,
                              void* d_out, int out_size, void* d_ws, size_t ws_size,
                              hipStream_t stream) {
    const float* x    = (const float*)d_in[0];
    const float* rgb  = (const float*)d_in[1];
    const float* g_w  = (const float*)d_in[2];
    const float* g_b  = (const float*)d_in[3];
    const float* th_w = (const float*)d_in[4];
    const float* th_b = (const float*)d_in[5];
    const float* ph_w = (const float*)d_in[6];
    const float* ph_b = (const float*)d_in[7];
    const float* W_w  = (const float*)d_in[8];
    const float* W_b  = (const float*)d_in[9];
    const float* rg_w = (const float*)d_in[10];
    const float* rg_b = (const float*)d_in[11];
    const float* rt_w = (const float*)d_in[12];
    const float* rt_b = (const float*)d_in[13];
    const float* rp_w = (const float*)d_in[14];
    const float* rp_b = (const float*)d_in[15];
    const float* rW_w = (const float*)d_in[16];
    const float* rW_b = (const float*)d_in[17];
    const float* cp_w = (const float*)d_in[18];
    float* out = (float*)d_out;

    const size_t FIP = (size_t)F_ * I_ * P_;   // 4718592
    const size_t SKP = (size_t)F_ * KK_ * P_;  // 10027008

    u16* Gb  = (u16*)d_ws;            // [f][i2][p][2] bf16
    u16* THb = Gb  + FIP;             // [f][i2][p][2] bf16
    u16* PHb = THb + FIP;             // [f][i2][p][2] bf16
    u16* Sb  = PHb + FIP;             // [k][p][f1] bf16
    u16* Yp  = Sb  + SKP;             // [4][f][ib][p][8] bf16
    u16* Yr  = Yp  + 4 * FIP;         // [f][ib][p][8] bf16
    float* GR  = (float*)(Yr + FIP);  // [i][p] fp32
    float* SR  = GR + (size_t)I_ * P_;
    float* Bf  = SR + P_;
    float* DEN = Bf + (size_t)F_ * P_;        // [4][f][p]
    float* VT  = DEN + 4 * (size_t)F_ * P_;
    float* U   = VT + C_;
    float* CT  = U + C_;
    float* gT  = CT + 16;
    float* thT = gT  + (size_t)C_ * I_;
    float* phT = thT + (size_t)C_ * I_;
    float* rgT = phT + (size_t)C_ * I_;
    float* WT  = rgT + (size_t)C_ * I_;
    float* rWT = WT  + (size_t)C_ * I_;

    // weight prep
    k_prep<<<1, 128, 0, stream>>>(rt_w, rp_w, rt_b, rp_b, cp_w, VT, U, CT);
    k_tr<<<dim3(32, 6), 256, 0, stream>>>(g_w, th_w, ph_w, rg_w, W_w, rW_w,
                                          gT, thT, phT, rgT, WT, rWT);

    // projections of x -> bf16 i-pair packed (G, TH, PH) + Bf fold (i-block 32)
    k_conv3<<<dim3(P_ / 1024, 2, 24), 256, 0, stream>>>(x, gT, thT, phT,
                                                        g_b, th_b, ph_b, U, CT,
                                                        Gb, THb, PHb, Bf);

    // rgb-side: GR conv + SR field
    k_rg<<<dim3(P_ / 256, 5), 256, 0, stream>>>(rgb, rgT, rg_b, VT, CT, GR, SR);

    // attention scores (exp folded, bf16 out; S layout [k][p][f1])
    k_scores<<<dim3(P_ / 256, KK_ / 4), 256, 0, stream>>>(PHb, THb, Sb);

    // attention apply, f2 quarters -> bf16 partials [qtr][f][ib][p][8] + den partials
    k_y<<<dim3(P_ / 256, I_ / 8, 4), 256, 0, stream>>>(Sb, Gb, Yp, DEN);

    // rgb-branch tap-sum over i (GR shared across f) -> Yr [f][ib][p][8]
    k_yr<<<dim3(P_ / 128, I_ / 8), 128, 0, stream>>>(SR, Bf, GR, Yr);

    // final: combine partials, two packed-FMA convs, biases + residual (c-block 32)
    k_final<<<dim3(P_ / 256, F_, C_ / 32), 256, 0, stream>>>(Yp, Yr, DEN, WT, rWT,
                                                             W_b, rW_b, x, out);
}